// Round 3
// baseline (464.332 us; speedup 1.0000x reference)
//
#include <hip/hip_runtime.h>

#define N_DIM 32
#define NPB 128              // nodes per bucket
#define NB_MAX 1024          // max buckets supported (n_nodes <= 131072)
#define EPB 4096             // edges per partition/hist block (16 per thread)

// ---- Pass 0: bucket histogram with LDS pre-aggregation ----
__global__ __launch_bounds__(256) void k_bhist(const int* __restrict__ dst,
                                               int* __restrict__ gcount,
                                               int n_edges, int nb) {
    __shared__ int h[NB_MAX];
    const int t = threadIdx.x;
    for (int i = t; i < nb; i += 256) h[i] = 0;
    __syncthreads();
    const int start = blockIdx.x * EPB;
#pragma unroll
    for (int k = 0; k < 16; ++k) {
        int e = start + t + k * 256;
        if (e < n_edges) atomicAdd(&h[dst[e] >> 7], 1);
    }
    __syncthreads();
    for (int i = t; i < nb; i += 256) {
        int c = h[i];
        if (c) atomicAdd(&gcount[i], c);
    }
}

// ---- Pass 0b: exclusive scan of bucket counts (1 block) ----
__global__ __launch_bounds__(1024) void k_bscan(const int* __restrict__ gcount,
                                                int* __restrict__ base,
                                                int* __restrict__ cursor,
                                                int nb) {
    __shared__ int sc[1024];
    const int t = threadIdx.x;
    int v = (t < nb) ? gcount[t] : 0;
    sc[t] = v;
    __syncthreads();
    for (int off = 1; off < 1024; off <<= 1) {
        int x = (t >= off) ? sc[t - off] : 0;
        __syncthreads();
        sc[t] += x;
        __syncthreads();
    }
    if (t < nb) {
        int excl = sc[t] - v;
        base[t] = excl;
        cursor[t] = excl;
        if (t == nb - 1) base[nb] = sc[t];
    }
}

// ---- Pass 1: partition edges into buckets; pack src(17b) | dstLocal(7b)<<17 ----
__global__ __launch_bounds__(256) void k_part(const int* __restrict__ src,
                                              const int* __restrict__ dst,
                                              int* __restrict__ cursor,
                                              int* __restrict__ pairs,
                                              int n_edges, int nb) {
    __shared__ int h[NB_MAX];      // per-block bucket counts (then unused)
    __shared__ int gb[NB_MAX];     // per-block global base per bucket
    const int t = threadIdx.x;
    for (int i = t; i < nb; i += 256) h[i] = 0;
    __syncthreads();
    const int start = blockIdx.x * EPB;

    int bw[16];   // bucket | dstLocal<<16, or -1
    int rk[16];   // rank within (block, bucket)
#pragma unroll
    for (int k = 0; k < 16; ++k) {
        int e = start + t + k * 256;
        if (e < n_edges) {
            int d = dst[e];
            int b = d >> 7;
            bw[k] = b | ((d & (NPB - 1)) << 16);
            rk[k] = atomicAdd(&h[b], 1);
        } else {
            bw[k] = -1;
        }
    }
    __syncthreads();
    for (int i = t; i < nb; i += 256) {
        int c = h[i];
        gb[i] = c ? atomicAdd(&cursor[i], c) : 0;
    }
    __syncthreads();
#pragma unroll
    for (int k = 0; k < 16; ++k) {
        if (bw[k] >= 0) {
            int e = start + t + k * 256;
            int b = bw[k] & 0xFFFF;
            int dl = bw[k] >> 16;
            pairs[gb[b] + rk[k]] = src[e] | (dl << 17);
        }
    }
}

// ---- Pass 2: per-bucket aggregate (LDS float atomics) + matvec W ----
__global__ __launch_bounds__(256) void k_aggemm(const float* __restrict__ X,
                                                const float* __restrict__ W,
                                                const int* __restrict__ base,
                                                const int* __restrict__ pairs,
                                                float* __restrict__ out,
                                                int n_nodes) {
    __shared__ float acc[NPB][N_DIM + 1];    // pad -> conflict-free epilogue
    __shared__ float Wlds[N_DIM * N_DIM];
    const int t = threadIdx.x;

    for (int i = t; i < N_DIM * N_DIM; i += 256) Wlds[i] = W[i];
    float* accf = &acc[0][0];
    for (int i = t; i < NPB * (N_DIM + 1); i += 256) accf[i] = 0.0f;
    __syncthreads();

    const int b = blockIdx.x;
    const int e0 = base[b];
    const int e1 = base[b + 1];
    const int j = t & 7;                     // column-quad 0..7

    for (int e = e0 + (t >> 3); e < e1; e += 32) {
        int p = pairs[e];
        int s = p & 0x1FFFF;
        int dl = p >> 17;
        float4 v = ((const float4*)X)[(size_t)s * (N_DIM / 4) + j];
        atomicAdd(&acc[dl][4 * j + 0], v.x);
        atomicAdd(&acc[dl][4 * j + 1], v.y);
        atomicAdd(&acc[dl][4 * j + 2], v.z);
        atomicAdd(&acc[dl][4 * j + 3], v.w);
    }
    __syncthreads();

    const int ln = t >> 3;                   // 32 nodes per iteration
#pragma unroll
    for (int it = 0; it < NPB / 32; ++it) {
        const int nl = it * 32 + ln;
        const int node = b * NPB + nl;
        if (node < n_nodes) {
            float o0 = 0.f, o1 = 0.f, o2 = 0.f, o3 = 0.f;
#pragma unroll
            for (int k = 0; k < N_DIM; ++k) {
                const float a = acc[nl][k];
                o0 = fmaf(a, Wlds[k * N_DIM + 4 * j + 0], o0);
                o1 = fmaf(a, Wlds[k * N_DIM + 4 * j + 1], o1);
                o2 = fmaf(a, Wlds[k * N_DIM + 4 * j + 2], o2);
                o3 = fmaf(a, Wlds[k * N_DIM + 4 * j + 3], o3);
            }
            ((float4*)out)[(size_t)node * (N_DIM / 4) + j] =
                make_float4(o0, o1, o2, o3);
        }
    }
}

extern "C" void kernel_launch(void* const* d_in, const int* in_sizes, int n_in,
                              void* d_out, int out_size, void* d_ws, size_t ws_size,
                              hipStream_t stream) {
    const float* X   = (const float*)d_in[0];
    const float* W   = (const float*)d_in[1];
    const int*   src = (const int*)d_in[2];
    const int*   dst = (const int*)d_in[3];
    float* out = (float*)d_out;

    const int n_nodes = in_sizes[0] / N_DIM;
    const int n_edges = in_sizes[2];
    const int nb = (n_nodes + NPB - 1) / NPB;      // 782 buckets

    // workspace layout (ints)
    int* gcount = (int*)d_ws;          // nb
    int* base   = gcount + NB_MAX;     // nb + 1
    int* cursor = base + NB_MAX + 1;   // nb
    int* pairs  = cursor + NB_MAX;     // n_edges

    hipMemsetAsync(gcount, 0, (size_t)nb * sizeof(int), stream);

    const int nblk_e = (n_edges + EPB - 1) / EPB;  // 391
    k_bhist<<<nblk_e, 256, 0, stream>>>(dst, gcount, n_edges, nb);
    k_bscan<<<1, 1024, 0, stream>>>(gcount, base, cursor, nb);
    k_part<<<nblk_e, 256, 0, stream>>>(src, dst, cursor, pairs, n_edges, nb);
    k_aggemm<<<nb, 256, 0, stream>>>(X, W, base, pairs, out, n_nodes);
}

// Round 4
// 433.235 us; speedup vs baseline: 1.0718x; 1.0718x over previous
//
#include <hip/hip_runtime.h>

#define N_DIM 32
#define NPB 64               // nodes per bucket
#define NPB_SHIFT 6
#define NB_MAX 2048          // max buckets (n_nodes <= 131072)
#define EPB 4096             // edges per hist/partition block (16 per thread)

// ---- Pass 0: bucket histogram with LDS pre-aggregation ----
__global__ __launch_bounds__(256) void k_bhist(const int* __restrict__ dst,
                                               int* __restrict__ gcount,
                                               int n_edges, int nb) {
    __shared__ int h[NB_MAX];
    const int t = threadIdx.x;
    for (int i = t; i < nb; i += 256) h[i] = 0;
    __syncthreads();
    const int start = blockIdx.x * EPB;
#pragma unroll
    for (int k = 0; k < 16; ++k) {
        int e = start + t + k * 256;
        if (e < n_edges) atomicAdd(&h[dst[e] >> NPB_SHIFT], 1);
    }
    __syncthreads();
    for (int i = t; i < nb; i += 256) {
        int c = h[i];
        if (c) atomicAdd(&gcount[i], c);
    }
}

// ---- Pass 0b: exclusive scan of bucket counts (1 block, nb <= 2048) ----
__global__ __launch_bounds__(1024) void k_bscan(const int* __restrict__ gcount,
                                                int* __restrict__ base,
                                                int* __restrict__ cursor,
                                                int nb) {
    __shared__ int sc[1024];
    const int t = threadIdx.x;
    const int i0 = 2 * t, i1 = 2 * t + 1;
    int v0 = (i0 < nb) ? gcount[i0] : 0;
    int v1 = (i1 < nb) ? gcount[i1] : 0;
    int s = v0 + v1;
    sc[t] = s;
    __syncthreads();
    for (int off = 1; off < 1024; off <<= 1) {
        int x = (t >= off) ? sc[t - off] : 0;
        __syncthreads();
        sc[t] += x;
        __syncthreads();
    }
    int ex = sc[t] - s;             // exclusive over pair-sums
    if (i0 < nb) { base[i0] = ex;      cursor[i0] = ex; }
    if (i1 < nb) { base[i1] = ex + v0; cursor[i1] = ex + v0; }
    if (t == 1023) base[nb] = sc[1023];   // grand total
}

// ---- Pass 1: partition edges; pack src(17b) | dstLocal(6b)<<17 ----
__global__ __launch_bounds__(256) void k_part(const int* __restrict__ src,
                                              const int* __restrict__ dst,
                                              int* __restrict__ cursor,
                                              int* __restrict__ pairs,
                                              int n_edges, int nb) {
    __shared__ int h[NB_MAX];
    __shared__ int gb[NB_MAX];
    const int t = threadIdx.x;
    for (int i = t; i < nb; i += 256) h[i] = 0;
    __syncthreads();
    const int start = blockIdx.x * EPB;

    int bw[16];   // bucket | dl<<16, or -1
    int rk[16];
#pragma unroll
    for (int k = 0; k < 16; ++k) {
        int e = start + t + k * 256;
        if (e < n_edges) {
            int d = dst[e];
            int b = d >> NPB_SHIFT;
            bw[k] = b | ((d & (NPB - 1)) << 16);
            rk[k] = atomicAdd(&h[b], 1);
        } else {
            bw[k] = -1;
        }
    }
    __syncthreads();
    for (int i = t; i < nb; i += 256) {
        int c = h[i];
        gb[i] = c ? atomicAdd(&cursor[i], c) : 0;
    }
    __syncthreads();
#pragma unroll
    for (int k = 0; k < 16; ++k) {
        if (bw[k] >= 0) {
            int e = start + t + k * 256;
            int b = bw[k] & 0xFFFF;
            int dl = bw[k] >> 16;
            pairs[gb[b] + rk[k]] = src[e] | (dl << 17);
        }
    }
}

// ---- Pass 2: per-bucket aggregate + matvec, 4-edge MLP batching ----
// 8 lanes per edge (lane j owns columns 4j..4j+3); each 8-lane group
// processes 4 consecutive edges per iteration -> 4 gathers in flight.
__global__ __launch_bounds__(256) void k_aggemm(const float* __restrict__ X,
                                                const float* __restrict__ W,
                                                const int* __restrict__ base,
                                                const int* __restrict__ pairs,
                                                float* __restrict__ out,
                                                int n_nodes) {
    __shared__ float acc[NPB][N_DIM + 1];
    __shared__ float Wlds[N_DIM * N_DIM];
    const int t = threadIdx.x;

    for (int i = t; i < N_DIM * N_DIM; i += 256) Wlds[i] = W[i];
    float* accf = &acc[0][0];
    for (int i = t; i < NPB * (N_DIM + 1); i += 256) accf[i] = 0.0f;
    __syncthreads();

    const int b = blockIdx.x;
    const int e0 = base[b];
    const int e1 = base[b + 1];
    const int g = t >> 3;               // edge-group 0..31
    const int j = t & 7;                // column-quad 0..7
    const float4* X4 = (const float4*)X;

    for (int eb = e0 + g * 4; eb < e1; eb += 128) {
        const int n = e1 - eb;          // >= 1
        int p0 = pairs[eb];
        int p1 = (n > 1) ? pairs[eb + 1] : p0;
        int p2 = (n > 2) ? pairs[eb + 2] : p0;
        int p3 = (n > 3) ? pairs[eb + 3] : p0;
        // 4 independent gathers in flight
        float4 v0 = X4[(size_t)(p0 & 0x1FFFF) * (N_DIM / 4) + j];
        float4 v1 = X4[(size_t)(p1 & 0x1FFFF) * (N_DIM / 4) + j];
        float4 v2 = X4[(size_t)(p2 & 0x1FFFF) * (N_DIM / 4) + j];
        float4 v3 = X4[(size_t)(p3 & 0x1FFFF) * (N_DIM / 4) + j];
        {
            float* a = &acc[p0 >> 17][4 * j];
            atomicAdd(a + 0, v0.x); atomicAdd(a + 1, v0.y);
            atomicAdd(a + 2, v0.z); atomicAdd(a + 3, v0.w);
        }
        if (n > 1) {
            float* a = &acc[p1 >> 17][4 * j];
            atomicAdd(a + 0, v1.x); atomicAdd(a + 1, v1.y);
            atomicAdd(a + 2, v1.z); atomicAdd(a + 3, v1.w);
        }
        if (n > 2) {
            float* a = &acc[p2 >> 17][4 * j];
            atomicAdd(a + 0, v2.x); atomicAdd(a + 1, v2.y);
            atomicAdd(a + 2, v2.z); atomicAdd(a + 3, v2.w);
        }
        if (n > 3) {
            float* a = &acc[p3 >> 17][4 * j];
            atomicAdd(a + 0, v3.x); atomicAdd(a + 1, v3.y);
            atomicAdd(a + 2, v3.z); atomicAdd(a + 3, v3.w);
        }
    }
    __syncthreads();

    const int ln = t >> 3;              // 32 nodes per epilogue iter
#pragma unroll
    for (int it = 0; it < NPB / 32; ++it) {
        const int nl = it * 32 + ln;
        const int node = b * NPB + nl;
        if (node < n_nodes) {
            float o0 = 0.f, o1 = 0.f, o2 = 0.f, o3 = 0.f;
#pragma unroll
            for (int k = 0; k < N_DIM; ++k) {
                const float a = acc[nl][k];
                o0 = fmaf(a, Wlds[k * N_DIM + 4 * j + 0], o0);
                o1 = fmaf(a, Wlds[k * N_DIM + 4 * j + 1], o1);
                o2 = fmaf(a, Wlds[k * N_DIM + 4 * j + 2], o2);
                o3 = fmaf(a, Wlds[k * N_DIM + 4 * j + 3], o3);
            }
            ((float4*)out)[(size_t)node * (N_DIM / 4) + j] =
                make_float4(o0, o1, o2, o3);
        }
    }
}

extern "C" void kernel_launch(void* const* d_in, const int* in_sizes, int n_in,
                              void* d_out, int out_size, void* d_ws, size_t ws_size,
                              hipStream_t stream) {
    const float* X   = (const float*)d_in[0];
    const float* W   = (const float*)d_in[1];
    const int*   src = (const int*)d_in[2];
    const int*   dst = (const int*)d_in[3];
    float* out = (float*)d_out;

    const int n_nodes = in_sizes[0] / N_DIM;
    const int n_edges = in_sizes[2];
    const int nb = (n_nodes + NPB - 1) / NPB;      // 1563 buckets

    // workspace layout (ints)
    int* gcount = (int*)d_ws;          // nb
    int* base   = gcount + NB_MAX;     // nb + 1
    int* cursor = base + NB_MAX + 1;   // nb
    int* pairs  = cursor + NB_MAX;     // n_edges

    hipMemsetAsync(gcount, 0, (size_t)nb * sizeof(int), stream);

    const int nblk_e = (n_edges + EPB - 1) / EPB;  // 391
    k_bhist<<<nblk_e, 256, 0, stream>>>(dst, gcount, n_edges, nb);
    k_bscan<<<1, 1024, 0, stream>>>(gcount, base, cursor, nb);
    k_part<<<nblk_e, 256, 0, stream>>>(src, dst, cursor, pairs, n_edges, nb);
    k_aggemm<<<nb, 256, 0, stream>>>(X, W, base, pairs, out, n_nodes);
}